// Round 10
// baseline (482.868 us; speedup 1.0000x reference)
//
#include <hip/hip_runtime.h>

// Problem constants (fixed by the reference file)
#define BATCH   8
#define NVERT   50000
#define CIN     32
#define LSP     9
#define COUT    64
#define MVERT   12500
#define NNZ     37500

#define NFRAG   2304           // 9 s * 4 g * 64 lanes (B fragments)
#define OUTDW   (BATCH * MVERT * COUT)

#define TILE_T  128            // tasks per block (32 per wave, 2 M-tiles)
#define TPB     293            // ceil(37500/128)

#define PRE_BLOCKS   6250
#define PACK_BLOCKS  9
#define ZERO_BLOCKS  6250

#define HWORDS  6400           // 12800 packed u16 counters (>= MVERT), 25.6 KB

typedef __attribute__((ext_vector_type(8))) short  short8;
typedef __attribute__((ext_vector_type(4))) float  floatx4;

static __device__ __forceinline__ unsigned short f2bf(float f) {
    union { float f; unsigned int u; } c; c.f = f;
    unsigned int u = c.u;
    return (unsigned short)((u + 0x7fffu + ((u >> 16) & 1u)) >> 16);
}

// ---- k1: block 0 = ENTIRE sort pipeline in LDS (hist -> scan -> scatter,
// __syncthreads only -- no gbar, no memset, no extra dispatches); blocks 1..
// stream precast-x / pack-W / zero-out concurrently (independent work).
// Rationale: r9 proved sorting is worth 31 us in the main kernel (atomics
// are 3.3 ns each, 9.75M sorted vs 18.75M unsorted) but r0/r2 paid ~40 us
// of dispatch-chain setup for it. This gets the sort for free: ~4 MB of
// sort I/O hidden under ~100 MB of streaming, 2 dispatches total.
// hist/off2 live in ONE packed LDS array (2 x u16 per word; counts and
// positions < 65536). 26 KB static LDS -> streaming blocks still 6/CU.
__global__ __launch_bounds__(256)
void prep_sort_kernel(const float* __restrict__ x, const float* __restrict__ w,
                      const int* __restrict__ rows, const int* __restrict__ cols,
                      const float* __restrict__ vals, const int* __restrict__ spiral,
                      unsigned short* __restrict__ x16, unsigned short* __restrict__ wp,
                      float* __restrict__ out,
                      int* __restrict__ rows_s, float* __restrict__ vals_s,
                      unsigned short* __restrict__ tidx)
{
    __shared__ unsigned int lh[HWORDS];   // packed 2xu16 hist -> off2 (in place)
    __shared__ int sh[256];
    const int blk = blockIdx.x;
    const int tid = threadIdx.x;

    if (blk == 0) {
        // ---- phase 1: zero packed hist
        for (int i = tid; i < HWORDS; i += 256) lh[i] = 0u;
        __syncthreads();

        // ---- phase 2: histogram of rows (LDS atomics on 16-bit fields)
        for (int z = tid; z < NNZ; z += 256) {
            const int r = rows[z];
            atomicAdd(&lh[r >> 1], 1u << ((r & 1) * 16));
        }
        __syncthreads();

        // ---- phase 3: exclusive scan over 12800 packed entries.
        // Thread t owns words [t*25, t*25+25) = entries [t*50, t*50+50)
        // (even chunk => no word straddles threads; in-place rewrite safe).
        const int base = tid * 25;
        {
            unsigned int sum = 0;
            #pragma unroll 5
            for (int j = 0; j < 25; ++j) {
                unsigned int v = lh[base + j];
                sum += (v & 0xffffu) + (v >> 16);
            }
            sh[tid] = (int)sum;
        }
        __syncthreads();
        #pragma unroll
        for (int d = 1; d < 256; d <<= 1) {
            int u = (tid >= d) ? sh[tid - d] : 0;
            __syncthreads();
            sh[tid] += u;
            __syncthreads();
        }
        {
            unsigned int run = (unsigned int)(sh[tid]);
            // make exclusive: subtract own sum (recompute while rewriting)
            unsigned int own = 0;
            #pragma unroll 5
            for (int j = 0; j < 25; ++j) {
                unsigned int v = lh[base + j];
                own += (v & 0xffffu) + (v >> 16);
            }
            run -= own;
            #pragma unroll 5
            for (int j = 0; j < 25; ++j) {
                unsigned int v  = lh[base + j];
                unsigned int lo = v & 0xffffu, hi = v >> 16;
                lh[base + j] = run | ((run + lo) << 16);
                run += lo + hi;
            }
        }
        __syncthreads();

        // ---- phase 4: scatter into row-sorted order + packed spiral indices
        for (int z = tid; z < NNZ; z += 256) {
            const int r = rows[z];
            const int c = cols[z];
            const unsigned int sh16 = (unsigned int)((r & 1) * 16);
            const int pos = (int)((atomicAdd(&lh[r >> 1], 1u << sh16) >> sh16) & 0xffffu);
            rows_s[pos] = r;
            vals_s[pos] = vals[z];
            unsigned short t[16];
            #pragma unroll
            for (int s = 0; s < 9; ++s) t[s] = (unsigned short)spiral[c * LSP + s];
            #pragma unroll
            for (int s = 9; s < 16; ++s) t[s] = 0;
            uint4* dst = (uint4*)(tidx + (size_t)pos * 16);
            dst[0] = *(uint4*)t;
            dst[1] = *(uint4*)(t + 8);
        }
        return;
    }

    // ---- streaming blocks: precast x | pack W | zero out (r2-proven shapes)
    const int pblk = blk - 1;
    if (pblk < PRE_BLOCKS) {
        const size_t base = ((size_t)pblk * 256 + tid) * 8;
        const float4* s = (const float4*)(x + base);
        float4 a = s[0], c = s[1];
        unsigned short t[8];
        t[0]=f2bf(a.x); t[1]=f2bf(a.y); t[2]=f2bf(a.z); t[3]=f2bf(a.w);
        t[4]=f2bf(c.x); t[5]=f2bf(c.y); t[6]=f2bf(c.z); t[7]=f2bf(c.w);
        *(uint4*)(x16 + base) = *(uint4*)t;
    } else if (pblk < PRE_BLOCKS + PACK_BLOCKS) {
        // B-frag f=(s*4+g)*64+lane holds W[s*32+(lane>>4)*8+j][g*16+(lane&15)]
        const int f = (pblk - PRE_BLOCKS) * 256 + tid;
        if (f < NFRAG) {
            int s = f >> 8, g = (f >> 6) & 3, lane = f & 63;
            int k0 = s * 32 + (lane >> 4) * 8, col = g * 16 + (lane & 15);
            unsigned short t[8];
            #pragma unroll
            for (int j = 0; j < 8; ++j)
                t[j] = f2bf(w[(size_t)(k0 + j) * COUT + col]);
            ((uint4*)wp)[f] = *(uint4*)t;
        }
    } else {
        const size_t base = ((size_t)(pblk - PRE_BLOCKS - PACK_BLOCKS) * 256 + tid) * 4;
        if (base < OUTDW) *(uint4*)(out + base) = (uint4){0, 0, 0, 0};
    }
}

// ---- k2: fused gather+GEMM+ELU+scale + register-aggregated scatter-add.
// EXACT r0 kernel (measured 52.6/54.0/54.2/54.4 across rounds). 32 tasks/
// wave, all 18 A-gathers up front, B-frags from global, zero LDS, zero
// barriers, run-compressed fire-and-forget atomics on row-sorted tasks
// (9.75M atomics ~= 32 us of the 54; sorting is what keeps it off 85 us).
__global__ __launch_bounds__(256, 3)
void spiral_mfma6_kernel(const unsigned short* __restrict__ x16,
                         const unsigned short* __restrict__ wp,
                         const float* __restrict__ bias,
                         const unsigned short* __restrict__ tidx,
                         const int* __restrict__ rows_s,
                         const float* __restrict__ vals_s,
                         float* __restrict__ out)
{
    const int bid  = blockIdx.x;
    const int b    = bid & 7;          // XCD swizzle: batch <-> XCD (x16/out L2-local)
    const int tile = bid >> 3;
    const int tid  = threadIdx.x;
    const int w    = tid >> 6;
    const int lane = tid & 63;
    const int quad = lane >> 4;
    const int m16  = lane & 15;
    const int z0w  = tile * TILE_T + 32 * w;   // wave's first sorted-task index

    // per-lane task metadata: lane L carries task z0w + (L&31) (coalesced)
    const int   zc   = min(z0w + (lane & 31), NNZ - 1);
    const int   rowv = rows_s[zc];
    const float valv = vals_s[zc];
    const uint4 p0 = *(const uint4*)(tidx + (size_t)zc * 16);
    const unsigned int p1 = *(const unsigned int*)(tidx + (size_t)zc * 16 + 8);
    int idx[9];
    idx[0] = p0.x & 0xffff;  idx[1] = p0.x >> 16;
    idx[2] = p0.y & 0xffff;  idx[3] = p0.y >> 16;
    idx[4] = p0.z & 0xffff;  idx[5] = p0.z >> 16;
    idx[6] = p0.w & 0xffff;  idx[7] = p0.w >> 16;
    idx[8] = p1 & 0xffff;

    const unsigned short* xb = x16 + (size_t)b * NVERT * CIN;

    // ---- all A-fragment gathers up front: one latency round-trip
    short8 A[2][9];
    #pragma unroll
    for (int s = 0; s < 9; ++s) {
        #pragma unroll
        for (int mt = 0; mt < 2; ++mt) {
            int tix = __shfl(idx[s], mt * 16 + m16);
            A[mt][s] = *(const short8*)(xb + (size_t)tix * CIN + quad * 8);
        }
    }

    floatx4 acc[2][4];
    #pragma unroll
    for (int mt = 0; mt < 2; ++mt)
        #pragma unroll
        for (int g = 0; g < 4; ++g) acc[mt][g] = (floatx4){0.f, 0.f, 0.f, 0.f};

    #pragma unroll
    for (int s = 0; s < 9; ++s) {
        short8 bf[4];
        #pragma unroll
        for (int g = 0; g < 4; ++g)
            bf[g] = *(const short8*)(wp + (size_t)((s * 4 + g) * 64 + lane) * 8);
        #pragma unroll
        for (int mt = 0; mt < 2; ++mt)
            #pragma unroll
            for (int g = 0; g < 4; ++g)
                acc[mt][g] = __builtin_amdgcn_mfma_f32_16x16x32_bf16(A[mt][s], bf[g], acc[mt][g], 0, 0, 0);
    }

    // ---- epilogue: register run-compression over 4 consecutive sorted tasks
    float bs[4];
    #pragma unroll
    for (int g = 0; g < 4; ++g) bs[g] = bias[g * 16 + m16];
    float* outb = out + (size_t)b * MVERT * COUT;

    #pragma unroll
    for (int mt = 0; mt < 2; ++mt) {
        int   rr[4]; float vv[4]; bool val[4];
        #pragma unroll
        for (int r = 0; r < 4; ++r) {
            const int tsk = mt * 16 + quad * 4 + r;        // C row = quad*4 + reg
            rr[r]  = __shfl(rowv, tsk);
            vv[r]  = __shfl(valv, tsk);
            val[r] = (z0w + tsk) < NNZ;
        }
        bool emit[4];   // last element of an equal-row run
        #pragma unroll
        for (int r = 0; r < 4; ++r)
            emit[r] = (r == 3) || (!val[r + 1 > 3 ? 3 : r + 1]) || (rr[r + 1 > 3 ? 3 : r + 1] != rr[r]);
        #pragma unroll
        for (int g = 0; g < 4; ++g) {
            const int ch = g * 16 + m16;
            float s = 0.0f;
            #pragma unroll
            for (int r = 0; r < 4; ++r) {
                if (val[r]) {
                    float y = acc[mt][g][r] + bs[g];
                    y = (y > 0.0f) ? y : (__expf(y) - 1.0f);
                    s += y * vv[r];
                    if (emit[r]) {
                        atomicAdd(outb + (size_t)rr[r] * COUT + ch, s);
                        s = 0.0f;
                    }
                }
            }
        }
    }
}

extern "C" void kernel_launch(void* const* d_in, const int* in_sizes, int n_in,
                              void* d_out, int out_size, void* d_ws, size_t ws_size,
                              hipStream_t stream) {
    const float* x      = (const float*)d_in[0];
    const float* w      = (const float*)d_in[1];
    const float* bias   = (const float*)d_in[2];
    const float* vals   = (const float*)d_in[3];
    const int*   spiral = (const int*)d_in[4];
    const int*   rows   = (const int*)d_in[5];
    const int*   cols   = (const int*)d_in[6];
    float* out = (float*)d_out;

    // ws layout (no hist/off2/barcnt: the sort lives entirely in LDS)
    char* base = (char*)d_ws;
    unsigned short* wp     = (unsigned short*)(base);                    //    36,864 B
    unsigned short* x16    = (unsigned short*)(base + 36864);            // 25,600,000 B
    int*            rows_s = (int*)(base + 25736880);                    //    150,000 B
    float*          vals_s = (float*)(base + 25886880);                  //    150,000 B
    unsigned short* tidx   = (unsigned short*)(base + 26186912);         //  1,200,000 B

    const int grid = 1 + PRE_BLOCKS + PACK_BLOCKS + ZERO_BLOCKS;
    prep_sort_kernel<<<grid, 256, 0, stream>>>(x, w, rows, cols, vals, spiral,
                                               x16, wp, out,
                                               rows_s, vals_s, tidx);
    spiral_mfma6_kernel<<<BATCH * TPB, 256, 0, stream>>>(x16, wp, bias, tidx,
                                                         rows_s, vals_s, out);
}